// Round 24
// baseline (100.618 us; speedup 1.0000x reference)
//
#include <hip/hip_runtime.h>
#include <math.h>

#define B_ 2
#define T_ 2048
#define D_ 512
#define H_ 8
#define DH_ 64
#define SCALE_ 0.125f
#define DECAY_ 0.99f

static constexpr size_t QSZ = (size_t)B_ * H_ * T_ * DH_; // 2,097,152 elems

typedef __bf16 bf16x8 __attribute__((ext_vector_type(8)));
typedef float f32x4 __attribute__((ext_vector_type(4)));

__device__ inline ushort f2bf(float f) {
  uint u = __float_as_uint(f);
  u += 0x7FFF + ((u >> 16) & 1);
  return (ushort)(u >> 16);
}

__device__ inline float bf2f(ushort v) {
  return __uint_as_float(((uint)v) << 16);
}

__device__ __forceinline__ void gload16(const ushort* g, ushort* l) {
  __builtin_amdgcn_global_load_lds(
      (const __attribute__((address_space(1))) void*)g,
      (__attribute__((address_space(3))) void*)l, 16, 0, 0);
}

__device__ __forceinline__ uint cvtpk(float lo, float hi) {
  uint r;
  asm("v_cvt_pk_bf16_f32 %0, %1, %2" : "=v"(r) : "v"(lo), "v"(hi));
  return r;  // D[15:0]=bf16(lo), D[31:16]=bf16(hi)
}

// ---------------- fused fp32 -> bf16 cast ----------------
__global__ __launch_bounds__(256) void cast_bf16_kernel(
    const float* __restrict__ x, const float* __restrict__ qkvw,
    const float* __restrict__ mvw, const float* __restrict__ ow,
    const float* __restrict__ w1w, const float* __restrict__ w2w,
    const float* __restrict__ w1r, const float* __restrict__ w2r,
    const float* __restrict__ mgw, ushort* __restrict__ dst)
{
  int bid = blockIdx.x;
  if (bid < 1024) bid = (bid & 7) * 128 + (bid >> 3);   // x-region XCD align
  size_t e0 = ((size_t)bid * 256 + threadIdx.x) * 8;
  const float* src = nullptr;
  if (e0 < 2097152)      src = x + e0;
  else if (e0 < 2883584) src = qkvw + (e0 - 2097152);
  else if (e0 < 3145728) src = mvw + (e0 - 2883584);
  else if (e0 < 3276800) {
    size_t off = e0 - 3145728;
    int row = (int)(off >> 9), col = (int)(off & 511);
    if (row < 32)       src = w1w + (size_t)row * 512 + col;
    else if (row < 64)  src = w2w + (size_t)(row - 32) * 512 + col;
    else if (row < 96)  src = w1r + (size_t)(row - 64) * 512 + col;
    else if (row < 128) src = w2r + (size_t)(row - 96) * 512 + col;
    else if (row < 136) src = mgw + (size_t)(row - 128) * 512 + col;
    else src = nullptr;
  } else if (e0 < 3538944) src = ow + (e0 - 3276800);
  ushort tmp[8];
  if (src) {
    float4 a = *(const float4*)(src);
    float4 b = *(const float4*)(src + 4);
    tmp[0] = f2bf(a.x); tmp[1] = f2bf(a.y); tmp[2] = f2bf(a.z); tmp[3] = f2bf(a.w);
    tmp[4] = f2bf(b.x); tmp[5] = f2bf(b.y); tmp[6] = f2bf(b.z); tmp[7] = f2bf(b.w);
  } else {
#pragma unroll
    for (int i = 0; i < 8; i++) tmp[i] = 0;
  }
  *(uint4*)(dst + e0) = *(uint4*)tmp;
}

// ---------------- MFMA GEMM, BM=64 BN=64 BK=64 (r21-proven), T2 swizzle -------
template<int EPI>
__global__ __launch_bounds__(256) void mfma_gemm(const ushort* __restrict__ A,
    const ushort* __restrict__ W, const float* __restrict__ bias,
    const float* __restrict__ bias2, void* __restrict__ Cout,
    ushort* __restrict__ memval16, float* __restrict__ proj, int M, int N, int K)
{
  __shared__ __align__(16) ushort As[64 * 64];    // 8 KB
  __shared__ __align__(16) ushort Ws[64 * 64];    // 8 KB
  const int tid = threadIdx.x;
  const int wave = tid >> 6, lane = tid & 63;
  const int col16 = lane & 15, grp = lane >> 4;
  const int wr = wave >> 1, wc = wave & 1;
  const int gx = gridDim.x;
  const int nwg = gx * gridDim.y;
  const int p = blockIdx.y * gx + blockIdx.x;
  const int wg = (p & 7) * (nwg >> 3) + (p >> 3);
  const int bm = (wg / gx) * 64, bn = (wg % gx) * 64;

  f32x4 acc[2][2] = {};
  const int lrow = lane >> 3;
  const int scol = (((lane & 7) ^ lrow) << 3);   // swizzled source chunk

  for (int k0 = 0; k0 < K; k0 += 64) {
    __syncthreads();
#pragma unroll
    for (int i = 0; i < 2; i++) {
      int q = i * 4 + wave;
      gload16(A + (size_t)(bm + q * 8 + lrow) * K + k0 + scol, &As[q * 512]);
      gload16(W + (size_t)(bn + q * 8 + lrow) * K + k0 + scol, &Ws[q * 512]);
    }
    __syncthreads();
#pragma unroll
    for (int kk = 0; kk < 2; kk++) {
      const int rchk = ((kk * 4 + grp) ^ (col16 & 7)) << 3;  // swizzled read chunk
      bf16x8 a[2], b[2];
#pragma unroll
      for (int m = 0; m < 2; m++)
        a[m] = *(const bf16x8*)&As[(wr * 32 + m * 16 + col16) * 64 + rchk];
#pragma unroll
      for (int n = 0; n < 2; n++)
        b[n] = *(const bf16x8*)&Ws[(wc * 32 + n * 16 + col16) * 64 + rchk];
#pragma unroll
      for (int m = 0; m < 2; m++)
#pragma unroll
        for (int n = 0; n < 2; n++)
          acc[m][n] = __builtin_amdgcn_mfma_f32_16x16x32_bf16(a[m], b[n], acc[m][n], 0, 0, 0);
    }
  }

  if (EPI == 1) {
    ushort* q16 = (ushort*)Cout;
    ushort* k16 = q16 + QSZ;
    ushort* vt  = q16 + 2 * QSZ;
    const int sec = bn >> 9;               // block-uniform
    if (sec == 2) {
#pragma unroll
      for (int n = 0; n < 2; n++) {
        int col = bn + wc * 32 + n * 16 + col16;
        float bv = bias[col];
        int h = (col >> 6) & 7, dh = col & 63;
#pragma unroll
        for (int m = 0; m < 2; m++) {
          int row0 = bm + wr * 32 + m * 16 + grp * 4;
          int b = row0 >> 11, t0 = row0 & 2047;
          // permuted j position (4 consecutive t stay consecutive)
          int tq = (t0 & ~63) + ((t0 >> 5) & 1) * 32 + ((t0 >> 2) & 3) * 8
                 + ((t0 >> 4) & 1) * 4;
          ushort tmp4[4];
#pragma unroll
          for (int r = 0; r < 4; r++) tmp4[r] = f2bf(acc[m][n][r] + bv);
          *(uint2*)(vt + ((size_t)(b * H_ + h) * 64 + dh) * T_ + tq) = *(uint2*)tmp4;
        }
      }
    } else {
#pragma unroll
      for (int n = 0; n < 2; n++) {
        int col = bn + wc * 32 + n * 16 + col16;
        float bv;
        if (sec < 2)       bv = bias[col];
        else if (sec == 3) bv = bias2[col - 1536];
        else               bv = 0.f;
        int h = (col >> 6) & 7, dh = col & 63;
#pragma unroll
        for (int m = 0; m < 2; m++) {
#pragma unroll
          for (int r = 0; r < 4; r++) {
            int row = bm + wr * 32 + m * 16 + grp * 4 + r;
            int b = row >> 11, t = row & 2047;
            float val = acc[m][n][r] + bv;
            size_t bh = (size_t)(b * H_ + h);
            if (sec == 0)      q16[(bh * T_ + t) * 64 + dh] = f2bf(val * (SCALE_ * 1.44269504f));
            else if (sec == 1) k16[(bh * T_ + t) * 64 + dh] = f2bf(val);
            else if (sec == 3) memval16[(size_t)row * 512 + (col - 1536)] = f2bf(val);
            else               proj[(size_t)row * 256 + (col - 2048)] = val;
          }
        }
      }
    }
  } else {
    float* C = (float*)Cout;
#pragma unroll
    for (int n = 0; n < 2; n++) {
      int col = bn + wc * 32 + n * 16 + col16;
      float bv = bias[col];
#pragma unroll
      for (int m = 0; m < 2; m++) {
#pragma unroll
        for (int r = 0; r < 4; r++) {
          int row = bm + wr * 32 + m * 16 + grp * 4 + r;
          C[(size_t)row * N + col] = acc[m][n][r] + bv;
        }
      }
    }
  }
}

// ------------- exterior lines + gate from proj rows -------------
__global__ __launch_bounds__(256) void lines_kernel(
    const float* __restrict__ proj, const float* __restrict__ gb,
    float* __restrict__ u_out, float* __restrict__ r_out, float* __restrict__ gate_out)
{
  int gid = blockIdx.x * 256 + threadIdx.x;
  int bt = gid >> 3, h = gid & 7;
  int b = bt >> 11, t = bt & 2047;
  const float* pr = proj + (size_t)bt * 256;
  const int pi[6] = {0, 0, 0, 1, 1, 2};
  const int pj[6] = {1, 2, 3, 2, 3, 3};
  float p1[4], p2[4];
#pragma unroll
  for (int e = 0; e < 4; e++) {
    p1[e] = (t == 0) ? 0.f : proj[(size_t)(bt - 1) * 256 + h * 4 + e];
    p2[e] = pr[32 + h * 4 + e];
  }
  float L[6], n2 = 0.f;
#pragma unroll
  for (int e = 0; e < 6; e++) {
    L[e] = p1[pi[e]] * p2[pj[e]] - p1[pj[e]] * p2[pi[e]];
    n2 = fmaf(L[e], L[e], n2);
  }
  float inv = 1.f / fmaxf(sqrtf(n2), 1e-12f);
  size_t base = (((size_t)(b * H_ + h)) * T_ + t) * 6;
  u_out[base + 0] =  L[5] * inv;
  u_out[base + 1] = -L[4] * inv;
  u_out[base + 2] =  L[3] * inv;
  u_out[base + 3] =  L[2] * inv;
  u_out[base + 4] = -L[1] * inv;
  u_out[base + 5] =  L[0] * inv;
#pragma unroll
  for (int e = 0; e < 4; e++) {
    p1[e] = pr[64 + h * 4 + e];
    p2[e] = pr[96 + h * 4 + e];
  }
  n2 = 0.f;
#pragma unroll
  for (int e = 0; e < 6; e++) {
    L[e] = p1[pi[e]] * p2[pj[e]] - p1[pj[e]] * p2[pi[e]];
    n2 = fmaf(L[e], L[e], n2);
  }
  inv = 1.f / fmaxf(sqrtf(n2), 1e-12f);
#pragma unroll
  for (int e = 0; e < 6; e++) r_out[base + e] = L[e] * inv;
  gate_out[(size_t)bt * H_ + h] = 1.f / (1.f + __expf(-(pr[128 + h] + gb[h])));
}

// ------------- memory score v3 (r8-proven) -------------
__global__ __launch_bounds__(128) void memscore3_kernel(
    const float* __restrict__ u, const float* __restrict__ r, float* __restrict__ score)
{
  const int bh = blockIdx.x;
  const int c = blockIdx.y;
  const int tid = threadIdx.x;
  const int base = c << 7;
  const int jmax = base + 128;
  __shared__ float us_t[6][2048];
  __shared__ float red[128][25];

  const float* ug = u + (size_t)bh * T_ * 6;
  for (int idx = tid; idx < jmax * 6; idx += 128) {
    int j = idx / 6;
    int cmp = idx - j * 6;
    us_t[cmp][j] = ug[idx];
  }
  __syncthreads();

  float g[21];
#pragma unroll
  for (int q2 = 0; q2 < 21; q2++) g[q2] = 0.f;
  if (c > 0) {
    float w = __powf(DECAY_, (float)(128 - tid));
    const float d128 = 0.27624712f;  // 0.99^128
    for (int j = base - 128 + tid; j >= 0; j -= 128) {
      float u0 = us_t[0][j], u1 = us_t[1][j], u2 = us_t[2][j];
      float u3 = us_t[3][j], u4 = us_t[4][j], u5 = us_t[5][j];
      float w0 = w * u0, w1 = w * u1, w2 = w * u2, w3 = w * u3, w4 = w * u4;
      g[0] = fmaf(w0, u0, g[0]);  g[1] = fmaf(w0, u1, g[1]);
      g[2] = fmaf(w0, u2, g[2]);  g[3] = fmaf(w0, u3, g[3]);
      g[4] = fmaf(w0, u4, g[4]);  g[5] = fmaf(w0, u5, g[5]);
      g[6] = fmaf(w1, u1, g[6]);  g[7] = fmaf(w1, u2, g[7]);
      g[8] = fmaf(w1, u3, g[8]);  g[9] = fmaf(w1, u4, g[9]);
      g[10] = fmaf(w1, u5, g[10]); g[11] = fmaf(w2, u2, g[11]);
      g[12] = fmaf(w2, u3, g[12]); g[13] = fmaf(w2, u4, g[13]);
      g[14] = fmaf(w2, u5, g[14]); g[15] = fmaf(w3, u3, g[15]);
      g[16] = fmaf(w3, u4, g[16]); g[17] = fmaf(w3, u5, g[17]);
      g[18] = fmaf(w4, u4, g[18]); g[19] = fmaf(w4, u5, g[19]);
      g[20] = fmaf(w * u5, u5, g[20]);
      w *= d128;
    }
  }
#pragma unroll
  for (int q2 = 0; q2 < 21; q2++) red[tid][q2] = g[q2];
  __syncthreads();
  for (int off = 64; off > 0; off >>= 1) {
    if (tid < off) {
#pragma unroll
      for (int q2 = 0; q2 < 21; q2++) red[tid][q2] += red[tid + off][q2];
    }
    __syncthreads();
  }
  float M21[21];
#pragma unroll
  for (int q2 = 0; q2 < 21; q2++) M21[q2] = red[0][q2];

  const int i = base + tid;
  const float* ri = r + ((size_t)bh * T_ + i) * 6;
  float r0 = ri[0], r1 = ri[1], r2 = ri[2], r3 = ri[3], r4 = ri[4], r5 = ri[5];
  float q = M21[0] * r0 * r0 + M21[6] * r1 * r1 + M21[11] * r2 * r2
          + M21[15] * r3 * r3 + M21[18] * r4 * r4 + M21[20] * r5 * r5
          + 2.f * (M21[1] * r0 * r1 + M21[2] * r0 * r2 + M21[3] * r0 * r3
                 + M21[4] * r0 * r4 + M21[5] * r0 * r5 + M21[7] * r1 * r2
                 + M21[8] * r1 * r3 + M21[9] * r1 * r4 + M21[10] * r1 * r5
                 + M21[12] * r2 * r3 + M21[13] * r2 * r4 + M21[14] * r2 * r5
                 + M21[16] * r3 * r4 + M21[17] * r3 * r5 + M21[19] * r4 * r5);
  float wl = __powf(DECAY_, (float)tid);
  float sum = q * wl;
  float w = wl;
  const float invd = 1.0f / DECAY_;
  const int sbound = tid | 63;           // wave-uniform bound
  for (int s = 0; s < sbound; ++s) {
    float d = r0 * us_t[0][base + s] + r1 * us_t[1][base + s]
            + r2 * us_t[2][base + s] + r3 * us_t[3][base + s]
            + r4 * us_t[4][base + s] + r5 * us_t[5][base + s];
    if (s < tid) sum = fmaf(w, d * d, sum);
    w *= invd;
  }
  score[(size_t)bh * T_ + i] = sum;
}

// ------------- attention v10: v9 + compact XOR-swizzled combine LDS -------------
// ocomb stride 32 floats (float4-aligned) + lane-XOR on fragment index keeps
// the combine conflict-free; LDS 30720 -> 26112 B => 6 blocks/CU (+20% waves).
// Writer and reader use the SAME lane -> XOR is transparent (both-sides).
__global__ __launch_bounds__(256) void attn_v10_kernel(
    const ushort* __restrict__ q16, const ushort* __restrict__ k16,
    const ushort* __restrict__ vtp16, const ushort* __restrict__ memval16,
    const float* __restrict__ score, const float* __restrict__ gate,
    const float* __restrict__ mscl, ushort* __restrict__ seqo16)
{
  const int blk = blockIdx.x;
  const int xcd = blk & 7, rank = blk >> 3;
  const int bh = (xcd << 1) | (rank & 1);
  const int rg = 63 - (rank >> 1);       // heavy-first within each XCD
  const int tid = threadIdx.x;
  const int w = tid >> 6, lane = tid & 63;
  const int col16 = lane & 15, grp = lane >> 4;

  __shared__ __align__(16) float ocomb[3][64][32];  // 24576 B
  __shared__ float lcomb[3][64][2];                 //  1536 B

  const int i0 = rg * 32;
  const ushort* qp0 = q16 + ((size_t)bh * T_ + i0 + col16) * 64 + grp * 8;
  bf16x8 aq[2][2];
  aq[0][0] = *(const bf16x8*)(qp0);
  aq[0][1] = *(const bf16x8*)(qp0 + 32);
  aq[1][0] = *(const bf16x8*)(qp0 + 16 * 64);
  aq[1][1] = *(const bf16x8*)(qp0 + 16 * 64 + 32);

  f32x4 ot[2][4] = {};
  float lsum[2] = {0.f, 0.f};

  const ushort* kb = k16 + (size_t)bh * T_ * 64;
  const ushort* vb = vtp16 + (size_t)bh * 64 * T_;

  const int ntiles = (rg >> 1) + 1;
  for (int kt = w; kt < ntiles; kt += 4) {
    const int j0 = kt * 64;
    bf16x8 vf[2][4];
#pragma unroll
    for (int ks = 0; ks < 2; ks++)
#pragma unroll
      for (int n4 = 0; n4 < 4; n4++)
        vf[ks][n4] = *(const bf16x8*)(vb + (size_t)(n4 * 16 + col16) * T_ +
                                      j0 + ks * 32 + grp * 8);
    const bool lastt = (kt == ntiles - 1);
    uint pk[2][4][2];
#pragma unroll
    for (int jt = 0; jt < 4; jt++) {
      const ushort* kp = kb + (size_t)(j0 + jt * 16 + col16) * 64 + grp * 8;
      bf16x8 b0 = *(const bf16x8*)kp;
      bf16x8 b1 = *(const bf16x8*)(kp + 32);
#pragma unroll
      for (int rr = 0; rr < 2; rr++) {
        f32x4 facc = {};
        __builtin_amdgcn_s_setprio(1);
        facc = __builtin_amdgcn_mfma_f32_16x16x32_bf16(b0, aq[rr][0], facc, 0, 0, 0);
        facc = __builtin_amdgcn_mfma_f32_16x16x32_bf16(b1, aq[rr][1], facc, 0, 0, 0);
        __builtin_amdgcn_s_setprio(0);
        const int i = i0 + rr * 16 + col16;
        float p[4];
#pragma unroll
        for (int r = 0; r < 4; r++) {
          int j = j0 + jt * 16 + grp * 4 + r;
          p[r] = (lastt && j > i) ? 0.f : exp2f(facc[r]);
          lsum[rr] += p[r];
        }
        pk[rr][jt][0] = cvtpk(p[0], p[1]);
        pk[rr][jt][1] = cvtpk(p[2], p[3]);
      }
    }
    __builtin_amdgcn_s_setprio(1);
#pragma unroll
    for (int ks = 0; ks < 2; ks++)
#pragma unroll
      for (int rr = 0; rr < 2; rr++) {
        uint pf_u[4] = {pk[rr][2 * ks][0], pk[rr][2 * ks][1],
                        pk[rr][2 * ks + 1][0], pk[rr][2 * ks + 1][1]};
        bf16x8 pf = *(bf16x8*)pf_u;
#pragma unroll
        for (int n4 = 0; n4 < 4; n4++)
          ot[rr][n4] = __builtin_amdgcn_mfma_f32_16x16x32_bf16(vf[ks][n4], pf, ot[rr][n4], 0, 0, 0);
      }
    __builtin_amdgcn_s_setprio(0);
  }

#pragma unroll
  for (int rr = 0; rr < 2; rr++) {
    lsum[rr] += __shfl_xor(lsum[rr], 16);
    lsum[rr] += __shfl_xor(lsum[rr], 32);
  }

  const int lx = lane & 7;               // XOR key (same for writer & reader)
  if (w > 0) {
    float* dst = &ocomb[w - 1][lane][0];
#pragma unroll
    for (int rr = 0; rr < 2; rr++)
#pragma unroll
      for (int n4 = 0; n4 < 4; n4++)
        *(float4*)&dst[((rr * 4 + n4) ^ lx) * 4] = *(float4*)&ot[rr][n4];
    lcomb[w - 1][lane][0] = lsum[0];
    lcomb[w - 1][lane][1] = lsum[1];
  }
  __syncthreads();
  if (w == 0) {
#pragma unroll
    for (int ww = 0; ww < 3; ww++) {
      const float* src = &ocomb[ww][lane][0];
#pragma unroll
      for (int rr = 0; rr < 2; rr++)
#pragma unroll
        for (int n4 = 0; n4 < 4; n4++) {
          float4 v = *(const float4*)&src[((rr * 4 + n4) ^ lx) * 4];
          ot[rr][n4][0] += v.x; ot[rr][n4][1] += v.y;
          ot[rr][n4][2] += v.z; ot[rr][n4][3] += v.w;
        }
      lsum[0] += lcomb[ww][lane][0];
      lsum[1] += lcomb[ww][lane][1];
    }
    const int b = bh >> 3, h = bh & 7;
#pragma unroll
    for (int rr = 0; rr < 2; rr++) {
      const int i = i0 + rr * 16 + col16;
      const float inv = 1.f / lsum[rr];
      // inline gfac: mean_h sigmoid(score[b,h,i]*mscl[h]) * gate[b,i,h]
      float gacc = 0.f;
#pragma unroll
      for (int hh = 0; hh < H_; hh++) {
        float ms = score[((size_t)(b * H_ + hh)) * T_ + i];
        float sg = 1.f / (1.f + __expf(-ms * mscl[hh]));
        gacc += sg * gate[((size_t)(b * T_ + i)) * H_ + hh];
      }
      const float gf = gacc * (1.0f / H_);
      const size_t rowbase = ((size_t)(b * T_) + i) * D_ + h * 64 + grp * 4;
#pragma unroll
      for (int n4 = 0; n4 < 4; n4++) {
        ushort tmp4[4];
#pragma unroll
        for (int r = 0; r < 4; r++) {
          float mv = bf2f(memval16[rowbase + n4 * 16 + r]);
          tmp4[r] = f2bf(fmaf(gf, mv, ot[rr][n4][r] * inv));
        }
        *(uint2*)(seqo16 + rowbase + n4 * 16) = *(uint2*)tmp4;
      }
    }
  }
}

extern "C" void kernel_launch(void* const* d_in, const int* in_sizes, int n_in,
                              void* d_out, int out_size, void* d_ws, size_t ws_size,
                              hipStream_t stream) {
  const float* x     = (const float*)d_in[0];
  const float* qkvw  = (const float*)d_in[1];
  const float* qkvb  = (const float*)d_in[2];
  const float* w1w   = (const float*)d_in[3];
  const float* w2w   = (const float*)d_in[4];
  const float* w1r   = (const float*)d_in[5];
  const float* w2r   = (const float*)d_in[6];
  const float* mvw   = (const float*)d_in[7];
  const float* mvb   = (const float*)d_in[8];
  const float* mgw   = (const float*)d_in[9];
  const float* mgb   = (const float*)d_in[10];
  const float* mscl  = (const float*)d_in[11];
  const float* ow    = (const float*)d_in[12];
  const float* ob    = (const float*)d_in[13];
  (void)in_sizes; (void)n_in; (void)out_size; (void)ws_size;

  float* f = (float*)d_ws;
  float* proj   = f;                              // 1,048,576 floats
  float* ul     = proj + 1048576;                 // 196,608
  float* rl     = ul + 196608;                    // 196,608
  float* gatep  = rl + 196608;                    // 32,768
  float* msc    = gatep + 32768;                  // 32,768
  float* gfac   = msc + 32768;                    // 4,096 (unused)
  ushort* x16    = (ushort*)(gfac + 4096);        // 2,097,152 (reused as seqo16)
  ushort* wbig16 = x16 + 2097152;                 // qkvw+mvw+wcat 1,179,648
  ushort* ow16   = wbig16 + 1179648;              // 262,144
  ushort* q16    = ow16 + 262144;                 // 2,097,152
  ushort* k16    = q16 + QSZ;                     // 2,097,152
  ushort* vt16   = k16 + QSZ;                     // 2,097,152 (j-permuted)
  ushort* memval16 = vt16 + QSZ;                  // 2,097,152
  ushort* seqo16 = x16;

  const int M = B_ * T_;

  cast_bf16_kernel<<<dim3(1728), 256, 0, stream>>>(x, qkvw, mvw, ow,
                                                   w1w, w2w, w1r, w2r, mgw, x16);
  // merged qkv + memval + proj GEMM: N = 2304, BM=BN=64 -> 36x64 = 2304 blocks
  mfma_gemm<1><<<dim3(36, 64), 256, 0, stream>>>(x16, wbig16, qkvb, mvb, q16,
                                                 memval16, proj, M, 2304, D_);
  lines_kernel<<<dim3(128), 256, 0, stream>>>(proj, mgb, ul, rl, gatep);
  memscore3_kernel<<<dim3(16, 16), 128, 0, stream>>>(ul, rl, msc);
  attn_v10_kernel<<<dim3(16 * 64), 256, 0, stream>>>(q16, k16, vt16, memval16,
                                                     msc, gatep, mscl, seqo16);
  // out GEMM: N = 512, BM=BN=64 -> 8x64 = 512 blocks
  mfma_gemm<0><<<dim3(8, 64), 256, 0, stream>>>(seqo16, ow16, ob, nullptr, d_out,
                                                nullptr, nullptr, M, D_, D_);
}

// Round 25
// 100.253 us; speedup vs baseline: 1.0036x; 1.0036x over previous
//
#include <hip/hip_runtime.h>
#include <math.h>

#define B_ 2
#define T_ 2048
#define D_ 512
#define H_ 8
#define DH_ 64
#define SCALE_ 0.125f
#define DECAY_ 0.99f

static constexpr size_t QSZ = (size_t)B_ * H_ * T_ * DH_; // 2,097,152 elems

typedef __bf16 bf16x8 __attribute__((ext_vector_type(8)));
typedef float f32x4 __attribute__((ext_vector_type(4)));

__device__ inline ushort f2bf(float f) {
  uint u = __float_as_uint(f);
  u += 0x7FFF + ((u >> 16) & 1);
  return (ushort)(u >> 16);
}

__device__ inline float bf2f(ushort v) {
  return __uint_as_float(((uint)v) << 16);
}

__device__ __forceinline__ void gload16(const ushort* g, ushort* l) {
  __builtin_amdgcn_global_load_lds(
      (const __attribute__((address_space(1))) void*)g,
      (__attribute__((address_space(3))) void*)l, 16, 0, 0);
}

__device__ __forceinline__ uint cvtpk(float lo, float hi) {
  uint r;
  asm("v_cvt_pk_bf16_f32 %0, %1, %2" : "=v"(r) : "v"(lo), "v"(hi));
  return r;  // D[15:0]=bf16(lo), D[31:16]=bf16(hi)
}

// ---------------- fused fp32 -> bf16 cast ----------------
__global__ __launch_bounds__(256) void cast_bf16_kernel(
    const float* __restrict__ x, const float* __restrict__ qkvw,
    const float* __restrict__ mvw, const float* __restrict__ ow,
    const float* __restrict__ w1w, const float* __restrict__ w2w,
    const float* __restrict__ w1r, const float* __restrict__ w2r,
    const float* __restrict__ mgw, ushort* __restrict__ dst)
{
  int bid = blockIdx.x;
  if (bid < 1024) bid = (bid & 7) * 128 + (bid >> 3);   // x-region XCD align
  size_t e0 = ((size_t)bid * 256 + threadIdx.x) * 8;
  const float* src = nullptr;
  if (e0 < 2097152)      src = x + e0;
  else if (e0 < 2883584) src = qkvw + (e0 - 2097152);
  else if (e0 < 3145728) src = mvw + (e0 - 2883584);
  else if (e0 < 3276800) {
    size_t off = e0 - 3145728;
    int row = (int)(off >> 9), col = (int)(off & 511);
    if (row < 32)       src = w1w + (size_t)row * 512 + col;
    else if (row < 64)  src = w2w + (size_t)(row - 32) * 512 + col;
    else if (row < 96)  src = w1r + (size_t)(row - 64) * 512 + col;
    else if (row < 128) src = w2r + (size_t)(row - 96) * 512 + col;
    else if (row < 136) src = mgw + (size_t)(row - 128) * 512 + col;
    else src = nullptr;
  } else if (e0 < 3538944) src = ow + (e0 - 3276800);
  ushort tmp[8];
  if (src) {
    float4 a = *(const float4*)(src);
    float4 b = *(const float4*)(src + 4);
    tmp[0] = f2bf(a.x); tmp[1] = f2bf(a.y); tmp[2] = f2bf(a.z); tmp[3] = f2bf(a.w);
    tmp[4] = f2bf(b.x); tmp[5] = f2bf(b.y); tmp[6] = f2bf(b.z); tmp[7] = f2bf(b.w);
  } else {
#pragma unroll
    for (int i = 0; i < 8; i++) tmp[i] = 0;
  }
  *(uint4*)(dst + e0) = *(uint4*)tmp;
}

// ---------------- MFMA GEMM, BM=64 BN=64 BK=64, T2 swizzle -------
template<int EPI>
__global__ __launch_bounds__(256) void mfma_gemm(const ushort* __restrict__ A,
    const ushort* __restrict__ W, const float* __restrict__ bias,
    const float* __restrict__ bias2, void* __restrict__ Cout,
    ushort* __restrict__ memval16, float* __restrict__ proj, int M, int N, int K)
{
  __shared__ __align__(16) ushort As[64 * 64];    // 8 KB
  __shared__ __align__(16) ushort Ws[64 * 64];    // 8 KB
  const int tid = threadIdx.x;
  const int wave = tid >> 6, lane = tid & 63;
  const int col16 = lane & 15, grp = lane >> 4;
  const int wr = wave >> 1, wc = wave & 1;
  const int gx = gridDim.x;
  const int nwg = gx * gridDim.y;
  const int p = blockIdx.y * gx + blockIdx.x;
  const int wg = (p & 7) * (nwg >> 3) + (p >> 3);
  const int bm = (wg / gx) * 64, bn = (wg % gx) * 64;

  f32x4 acc[2][2] = {};
  const int lrow = lane >> 3;
  const int scol = (((lane & 7) ^ lrow) << 3);   // swizzled source chunk

  for (int k0 = 0; k0 < K; k0 += 64) {
    __syncthreads();
#pragma unroll
    for (int i = 0; i < 2; i++) {
      int q = i * 4 + wave;
      gload16(A + (size_t)(bm + q * 8 + lrow) * K + k0 + scol, &As[q * 512]);
      gload16(W + (size_t)(bn + q * 8 + lrow) * K + k0 + scol, &Ws[q * 512]);
    }
    __syncthreads();
#pragma unroll
    for (int kk = 0; kk < 2; kk++) {
      const int rchk = ((kk * 4 + grp) ^ (col16 & 7)) << 3;  // swizzled read chunk
      bf16x8 a[2], b[2];
#pragma unroll
      for (int m = 0; m < 2; m++)
        a[m] = *(const bf16x8*)&As[(wr * 32 + m * 16 + col16) * 64 + rchk];
#pragma unroll
      for (int n = 0; n < 2; n++)
        b[n] = *(const bf16x8*)&Ws[(wc * 32 + n * 16 + col16) * 64 + rchk];
#pragma unroll
      for (int m = 0; m < 2; m++)
#pragma unroll
        for (int n = 0; n < 2; n++)
          acc[m][n] = __builtin_amdgcn_mfma_f32_16x16x32_bf16(a[m], b[n], acc[m][n], 0, 0, 0);
    }
  }

  if (EPI == 1) {
    ushort* q16 = (ushort*)Cout;
    ushort* k16 = q16 + QSZ;
    ushort* vt  = q16 + 2 * QSZ;
    const int sec = bn >> 9;               // block-uniform
    if (sec == 2) {
#pragma unroll
      for (int n = 0; n < 2; n++) {
        int col = bn + wc * 32 + n * 16 + col16;
        float bv = bias[col];
        int h = (col >> 6) & 7, dh = col & 63;
#pragma unroll
        for (int m = 0; m < 2; m++) {
          int row0 = bm + wr * 32 + m * 16 + grp * 4;
          int b = row0 >> 11, t0 = row0 & 2047;
          // permuted j position (4 consecutive t stay consecutive)
          int tq = (t0 & ~63) + ((t0 >> 5) & 1) * 32 + ((t0 >> 2) & 3) * 8
                 + ((t0 >> 4) & 1) * 4;
          ushort tmp4[4];
#pragma unroll
          for (int r = 0; r < 4; r++) tmp4[r] = f2bf(acc[m][n][r] + bv);
          *(uint2*)(vt + ((size_t)(b * H_ + h) * 64 + dh) * T_ + tq) = *(uint2*)tmp4;
        }
      }
    } else {
#pragma unroll
      for (int n = 0; n < 2; n++) {
        int col = bn + wc * 32 + n * 16 + col16;
        float bv;
        if (sec < 2)       bv = bias[col];
        else if (sec == 3) bv = bias2[col - 1536];
        else               bv = 0.f;
        int h = (col >> 6) & 7, dh = col & 63;
#pragma unroll
        for (int m = 0; m < 2; m++) {
#pragma unroll
          for (int r = 0; r < 4; r++) {
            int row = bm + wr * 32 + m * 16 + grp * 4 + r;
            int b = row >> 11, t = row & 2047;
            float val = acc[m][n][r] + bv;
            size_t bh = (size_t)(b * H_ + h);
            if (sec == 0)      q16[(bh * T_ + t) * 64 + dh] = f2bf(val * (SCALE_ * 1.44269504f));
            else if (sec == 1) k16[(bh * T_ + t) * 64 + dh] = f2bf(val);
            else if (sec == 3) memval16[(size_t)row * 512 + (col - 1536)] = f2bf(val);
            else               proj[(size_t)row * 256 + (col - 2048)] = val;
          }
        }
      }
    }
  } else {
    float* C = (float*)Cout;
#pragma unroll
    for (int n = 0; n < 2; n++) {
      int col = bn + wc * 32 + n * 16 + col16;
      float bv = bias[col];
#pragma unroll
      for (int m = 0; m < 2; m++) {
#pragma unroll
        for (int r = 0; r < 4; r++) {
          int row = bm + wr * 32 + m * 16 + grp * 4 + r;
          C[(size_t)row * N + col] = acc[m][n][r] + bv;
        }
      }
    }
  }
}

// ------------- exterior lines + gate from proj rows -------------
__global__ __launch_bounds__(256) void lines_kernel(
    const float* __restrict__ proj, const float* __restrict__ gb,
    float* __restrict__ u_out, float* __restrict__ r_out, float* __restrict__ gate_out)
{
  int gid = blockIdx.x * 256 + threadIdx.x;
  int bt = gid >> 3, h = gid & 7;
  int b = bt >> 11, t = bt & 2047;
  const float* pr = proj + (size_t)bt * 256;
  const int pi[6] = {0, 0, 0, 1, 1, 2};
  const int pj[6] = {1, 2, 3, 2, 3, 3};
  float p1[4], p2[4];
#pragma unroll
  for (int e = 0; e < 4; e++) {
    p1[e] = (t == 0) ? 0.f : proj[(size_t)(bt - 1) * 256 + h * 4 + e];
    p2[e] = pr[32 + h * 4 + e];
  }
  float L[6], n2 = 0.f;
#pragma unroll
  for (int e = 0; e < 6; e++) {
    L[e] = p1[pi[e]] * p2[pj[e]] - p1[pj[e]] * p2[pi[e]];
    n2 = fmaf(L[e], L[e], n2);
  }
  float inv = 1.f / fmaxf(sqrtf(n2), 1e-12f);
  size_t base = (((size_t)(b * H_ + h)) * T_ + t) * 6;
  u_out[base + 0] =  L[5] * inv;
  u_out[base + 1] = -L[4] * inv;
  u_out[base + 2] =  L[3] * inv;
  u_out[base + 3] =  L[2] * inv;
  u_out[base + 4] = -L[1] * inv;
  u_out[base + 5] =  L[0] * inv;
#pragma unroll
  for (int e = 0; e < 4; e++) {
    p1[e] = pr[64 + h * 4 + e];
    p2[e] = pr[96 + h * 4 + e];
  }
  n2 = 0.f;
#pragma unroll
  for (int e = 0; e < 6; e++) {
    L[e] = p1[pi[e]] * p2[pj[e]] - p1[pj[e]] * p2[pi[e]];
    n2 = fmaf(L[e], L[e], n2);
  }
  inv = 1.f / fmaxf(sqrtf(n2), 1e-12f);
#pragma unroll
  for (int e = 0; e < 6; e++) r_out[base + e] = L[e] * inv;
  gate_out[(size_t)bt * H_ + h] = 1.f / (1.f + __expf(-(pr[128 + h] + gb[h])));
}

// ------------- memory score v3 (r8-proven) -------------
__global__ __launch_bounds__(128) void memscore3_kernel(
    const float* __restrict__ u, const float* __restrict__ r, float* __restrict__ score)
{
  const int bh = blockIdx.x;
  const int c = blockIdx.y;
  const int tid = threadIdx.x;
  const int base = c << 7;
  const int jmax = base + 128;
  __shared__ float us_t[6][2048];
  __shared__ float red[128][25];

  const float* ug = u + (size_t)bh * T_ * 6;
  for (int idx = tid; idx < jmax * 6; idx += 128) {
    int j = idx / 6;
    int cmp = idx - j * 6;
    us_t[cmp][j] = ug[idx];
  }
  __syncthreads();

  float g[21];
#pragma unroll
  for (int q2 = 0; q2 < 21; q2++) g[q2] = 0.f;
  if (c > 0) {
    float w = __powf(DECAY_, (float)(128 - tid));
    const float d128 = 0.27624712f;  // 0.99^128
    for (int j = base - 128 + tid; j >= 0; j -= 128) {
      float u0 = us_t[0][j], u1 = us_t[1][j], u2 = us_t[2][j];
      float u3 = us_t[3][j], u4 = us_t[4][j], u5 = us_t[5][j];
      float w0 = w * u0, w1 = w * u1, w2 = w * u2, w3 = w * u3, w4 = w * u4;
      g[0] = fmaf(w0, u0, g[0]);  g[1] = fmaf(w0, u1, g[1]);
      g[2] = fmaf(w0, u2, g[2]);  g[3] = fmaf(w0, u3, g[3]);
      g[4] = fmaf(w0, u4, g[4]);  g[5] = fmaf(w0, u5, g[5]);
      g[6] = fmaf(w1, u1, g[6]);  g[7] = fmaf(w1, u2, g[7]);
      g[8] = fmaf(w1, u3, g[8]);  g[9] = fmaf(w1, u4, g[9]);
      g[10] = fmaf(w1, u5, g[10]); g[11] = fmaf(w2, u2, g[11]);
      g[12] = fmaf(w2, u3, g[12]); g[13] = fmaf(w2, u4, g[13]);
      g[14] = fmaf(w2, u5, g[14]); g[15] = fmaf(w3, u3, g[15]);
      g[16] = fmaf(w3, u4, g[16]); g[17] = fmaf(w3, u5, g[17]);
      g[18] = fmaf(w4, u4, g[18]); g[19] = fmaf(w4, u5, g[19]);
      g[20] = fmaf(w * u5, u5, g[20]);
      w *= d128;
    }
  }
#pragma unroll
  for (int q2 = 0; q2 < 21; q2++) red[tid][q2] = g[q2];
  __syncthreads();
  for (int off = 64; off > 0; off >>= 1) {
    if (tid < off) {
#pragma unroll
      for (int q2 = 0; q2 < 21; q2++) red[tid][q2] += red[tid + off][q2];
    }
    __syncthreads();
  }
  float M21[21];
#pragma unroll
  for (int q2 = 0; q2 < 21; q2++) M21[q2] = red[0][q2];

  const int i = base + tid;
  const float* ri = r + ((size_t)bh * T_ + i) * 6;
  float r0 = ri[0], r1 = ri[1], r2 = ri[2], r3 = ri[3], r4 = ri[4], r5 = ri[5];
  float q = M21[0] * r0 * r0 + M21[6] * r1 * r1 + M21[11] * r2 * r2
          + M21[15] * r3 * r3 + M21[18] * r4 * r4 + M21[20] * r5 * r5
          + 2.f * (M21[1] * r0 * r1 + M21[2] * r0 * r2 + M21[3] * r0 * r3
                 + M21[4] * r0 * r4 + M21[5] * r0 * r5 + M21[7] * r1 * r2
                 + M21[8] * r1 * r3 + M21[9] * r1 * r4 + M21[10] * r1 * r5
                 + M21[12] * r2 * r3 + M21[13] * r2 * r4 + M21[14] * r2 * r5
                 + M21[16] * r3 * r4 + M21[17] * r3 * r5 + M21[19] * r4 * r5);
  float wl = __powf(DECAY_, (float)tid);
  float sum = q * wl;
  float w = wl;
  const float invd = 1.0f / DECAY_;
  const int sbound = tid | 63;           // wave-uniform bound
  for (int s = 0; s < sbound; ++s) {
    float d = r0 * us_t[0][base + s] + r1 * us_t[1][base + s]
            + r2 * us_t[2][base + s] + r3 * us_t[3][base + s]
            + r4 * us_t[4][base + s] + r5 * us_t[5][base + s];
    if (s < tid) sum = fmaf(w, d * d, sum);
    w *= invd;
  }
  score[(size_t)bh * T_ + i] = sum;
}

// ------------- attention v9: swapped QK, in-register P, inline gfac -------------
__global__ __launch_bounds__(256) void attn_v9_kernel(
    const ushort* __restrict__ q16, const ushort* __restrict__ k16,
    const ushort* __restrict__ vtp16, const ushort* __restrict__ memval16,
    const float* __restrict__ score, const float* __restrict__ gate,
    const float* __restrict__ mscl, ushort* __restrict__ seqo16)
{
  const int blk = blockIdx.x;
  const int xcd = blk & 7, rank = blk >> 3;
  const int bh = (xcd << 1) | (rank & 1);
  const int rg = 63 - (rank >> 1);       // heavy-first within each XCD
  const int tid = threadIdx.x;
  const int w = tid >> 6, lane = tid & 63;
  const int col16 = lane & 15, grp = lane >> 4;

  __shared__ __align__(16) float comb[3][64][40];   // 30720 B (combine only)

  const int i0 = rg * 32;
  const ushort* qp0 = q16 + ((size_t)bh * T_ + i0 + col16) * 64 + grp * 8;
  bf16x8 aq[2][2];
  aq[0][0] = *(const bf16x8*)(qp0);
  aq[0][1] = *(const bf16x8*)(qp0 + 32);
  aq[1][0] = *(const bf16x8*)(qp0 + 16 * 64);
  aq[1][1] = *(const bf16x8*)(qp0 + 16 * 64 + 32);

  f32x4 ot[2][4] = {};
  float lsum[2] = {0.f, 0.f};

  const ushort* kb = k16 + (size_t)bh * T_ * 64;
  const ushort* vb = vtp16 + (size_t)bh * 64 * T_;

  const int ntiles = (rg >> 1) + 1;
  for (int kt = w; kt < ntiles; kt += 4) {
    const int j0 = kt * 64;
    bf16x8 vf[2][4];
#pragma unroll
    for (int ks = 0; ks < 2; ks++)
#pragma unroll
      for (int n4 = 0; n4 < 4; n4++)
        vf[ks][n4] = *(const bf16x8*)(vb + (size_t)(n4 * 16 + col16) * T_ +
                                      j0 + ks * 32 + grp * 8);
    const bool lastt = (kt == ntiles - 1);
    uint pk[2][4][2];
#pragma unroll
    for (int jt = 0; jt < 4; jt++) {
      const ushort* kp = kb + (size_t)(j0 + jt * 16 + col16) * 64 + grp * 8;
      bf16x8 b0 = *(const bf16x8*)kp;
      bf16x8 b1 = *(const bf16x8*)(kp + 32);
#pragma unroll
      for (int rr = 0; rr < 2; rr++) {
        f32x4 facc = {};
        __builtin_amdgcn_s_setprio(1);
        facc = __builtin_amdgcn_mfma_f32_16x16x32_bf16(b0, aq[rr][0], facc, 0, 0, 0);
        facc = __builtin_amdgcn_mfma_f32_16x16x32_bf16(b1, aq[rr][1], facc, 0, 0, 0);
        __builtin_amdgcn_s_setprio(0);
        const int i = i0 + rr * 16 + col16;
        float p[4];
#pragma unroll
        for (int r = 0; r < 4; r++) {
          int j = j0 + jt * 16 + grp * 4 + r;
          p[r] = (lastt && j > i) ? 0.f : exp2f(facc[r]);
          lsum[rr] += p[r];
        }
        pk[rr][jt][0] = cvtpk(p[0], p[1]);
        pk[rr][jt][1] = cvtpk(p[2], p[3]);
      }
    }
    __builtin_amdgcn_s_setprio(1);
#pragma unroll
    for (int ks = 0; ks < 2; ks++)
#pragma unroll
      for (int rr = 0; rr < 2; rr++) {
        uint pf_u[4] = {pk[rr][2 * ks][0], pk[rr][2 * ks][1],
                        pk[rr][2 * ks + 1][0], pk[rr][2 * ks + 1][1]};
        bf16x8 pf = *(bf16x8*)pf_u;
#pragma unroll
        for (int n4 = 0; n4 < 4; n4++)
          ot[rr][n4] = __builtin_amdgcn_mfma_f32_16x16x32_bf16(vf[ks][n4], pf, ot[rr][n4], 0, 0, 0);
      }
    __builtin_amdgcn_s_setprio(0);
  }

#pragma unroll
  for (int rr = 0; rr < 2; rr++) {
    lsum[rr] += __shfl_xor(lsum[rr], 16);
    lsum[rr] += __shfl_xor(lsum[rr], 32);
  }

  if (w > 0) {
    float* dst = &comb[w - 1][lane][0];
#pragma unroll
    for (int rr = 0; rr < 2; rr++)
#pragma unroll
      for (int n4 = 0; n4 < 4; n4++)
        *(float4*)&dst[(rr * 4 + n4) * 4] = *(float4*)&ot[rr][n4];
    dst[32] = lsum[0];
    dst[33] = lsum[1];
  }
  __syncthreads();
  if (w == 0) {
#pragma unroll
    for (int ww = 0; ww < 3; ww++) {
      const float* src = &comb[ww][lane][0];
#pragma unroll
      for (int rr = 0; rr < 2; rr++)
#pragma unroll
        for (int n4 = 0; n4 < 4; n4++) {
          float4 v = *(const float4*)&src[(rr * 4 + n4) * 4];
          ot[rr][n4][0] += v.x; ot[rr][n4][1] += v.y;
          ot[rr][n4][2] += v.z; ot[rr][n4][3] += v.w;
        }
      lsum[0] += src[32];
      lsum[1] += src[33];
    }
    const int b = bh >> 3, h = bh & 7;
#pragma unroll
    for (int rr = 0; rr < 2; rr++) {
      const int i = i0 + rr * 16 + col16;
      const float inv = 1.f / lsum[rr];
      // inline gfac: mean_h sigmoid(score[b,h,i]*mscl[h]) * gate[b,i,h]
      float gacc = 0.f;
#pragma unroll
      for (int hh = 0; hh < H_; hh++) {
        float ms = score[((size_t)(b * H_ + hh)) * T_ + i];
        float sg = 1.f / (1.f + __expf(-ms * mscl[hh]));
        gacc += sg * gate[((size_t)(b * T_ + i)) * H_ + hh];
      }
      const float gf = gacc * (1.0f / H_);
      const size_t rowbase = ((size_t)(b * T_) + i) * D_ + h * 64 + grp * 4;
#pragma unroll
      for (int n4 = 0; n4 < 4; n4++) {
        ushort tmp4[4];
#pragma unroll
        for (int r = 0; r < 4; r++) {
          float mv = bf2f(memval16[rowbase + n4 * 16 + r]);
          tmp4[r] = f2bf(fmaf(gf, mv, ot[rr][n4][r] * inv));
        }
        *(uint2*)(seqo16 + rowbase + n4 * 16) = *(uint2*)tmp4;
      }
    }
  }
}

extern "C" void kernel_launch(void* const* d_in, const int* in_sizes, int n_in,
                              void* d_out, int out_size, void* d_ws, size_t ws_size,
                              hipStream_t stream) {
  const float* x     = (const float*)d_in[0];
  const float* qkvw  = (const float*)d_in[1];
  const float* qkvb  = (const float*)d_in[2];
  const float* w1w   = (const float*)d_in[3];
  const float* w2w   = (const float*)d_in[4];
  const float* w1r   = (const float*)d_in[5];
  const float* w2r   = (const float*)d_in[6];
  const float* mvw   = (const float*)d_in[7];
  const float* mvb   = (const float*)d_in[8];
  const float* mgw   = (const float*)d_in[9];
  const float* mgb   = (const float*)d_in[10];
  const float* mscl  = (const float*)d_in[11];
  const float* ow    = (const float*)d_in[12];
  const float* ob    = (const float*)d_in[13];
  (void)in_sizes; (void)n_in; (void)out_size; (void)ws_size;

  float* f = (float*)d_ws;
  float* proj   = f;                              // 1,048,576 floats
  float* ul     = proj + 1048576;                 // 196,608
  float* rl     = ul + 196608;                    // 196,608
  float* gatep  = rl + 196608;                    // 32,768
  float* msc    = gatep + 32768;                  // 32,768
  float* gfac   = msc + 32768;                    // 4,096 (unused)
  ushort* x16    = (ushort*)(gfac + 4096);        // 2,097,152 (reused as seqo16)
  ushort* wbig16 = x16 + 2097152;                 // qkvw+mvw+wcat 1,179,648
  ushort* ow16   = wbig16 + 1179648;              // 262,144
  ushort* q16    = ow16 + 262144;                 // 2,097,152
  ushort* k16    = q16 + QSZ;                     // 2,097,152
  ushort* vt16   = k16 + QSZ;                     // 2,097,152 (j-permuted)
  ushort* memval16 = vt16 + QSZ;                  // 2,097,152
  ushort* seqo16 = x16;

  const int M = B_ * T_;

  cast_bf16_kernel<<<dim3(1728), 256, 0, stream>>>(x, qkvw, mvw, ow,
                                                   w1w, w2w, w1r, w2r, mgw, x16);
  // merged qkv + memval + proj GEMM: N = 2304, BM=BN=64 -> 36x64 = 2304 blocks
  mfma_gemm<1><<<dim3(36, 64), 256, 0, stream>>>(x16, wbig16, qkvb, mvb, q16,
                                                 memval16, proj, M, 2304, D_);
  lines_kernel<<<dim3(128), 256, 0, stream>>>(proj, mgb, ul, rl, gatep);
  memscore3_kernel<<<dim3(16, 16), 128, 0, stream>>>(ul, rl, msc);
  attn_v9_kernel<<<dim3(16 * 64), 256, 0, stream>>>(q16, k16, vt16, memval16,
                                                    msc, gatep, mscl, seqo16);
  // out GEMM: N = 512, BM=BN=64 -> 8x64 = 512 blocks
  mfma_gemm<0><<<dim3(8, 64), 256, 0, stream>>>(seqo16, ow16, ob, nullptr, d_out,
                                                nullptr, nullptr, M, D_, D_);
}